// Round 2
// baseline (1589.313 us; speedup 1.0000x reference)
//
#include <hip/hip_runtime.h>
#include <hip/hip_bf16.h>
#include <math.h>

// GCN 2-layer forward, MI355X. Structure:
//   deg/dinv -> CSR-by-dst (hist, scan, scatter) -> gemm1 -> agg1(+b1,relu)
//   -> gemm2 -> agg2(+b2,log_softmax)
// All f32. CSR gather avoids f32 atomics in the hot aggregation path.
// NOTE: harness delivers integer inputs as int32 (edge_index [2,E] row-major).

#define FIN 512
#define FHID 64
#define FOUT 40
#define SCAN_B 1024

__global__ void k_deg_init(float* __restrict__ deg, int n) {
    int i = blockIdx.x * blockDim.x + threadIdx.x;
    if (i < n) deg[i] = 1.0f;  // self-loop weight
}

__global__ void k_edge_pass1(const int* __restrict__ ei,
                             const float* __restrict__ ew,
                             float* __restrict__ deg, int* __restrict__ cnt, int E) {
    int e = blockIdx.x * blockDim.x + threadIdx.x;
    if (e >= E) return;
    int d = ei[E + e];
    atomicAdd(&deg[d], ew[e]);
    atomicAdd(&cnt[d], 1);
}

__global__ void k_dinv(float* __restrict__ deg, int n) {
    int i = blockIdx.x * blockDim.x + threadIdx.x;
    if (i < n) {
        float v = deg[i];
        deg[i] = (v > 0.0f) ? rsqrtf(v) : 0.0f;  // deg now holds dinv
    }
}

__global__ void k_scan1(const int* __restrict__ cnt, int* __restrict__ off,
                        int* __restrict__ bsum, int n) {
    __shared__ int s[SCAN_B];
    int tid = threadIdx.x;
    int gid = blockIdx.x * SCAN_B + tid;
    int v = (gid < n) ? cnt[gid] : 0;
    s[tid] = v;
    __syncthreads();
    for (int d = 1; d < SCAN_B; d <<= 1) {
        int t = (tid >= d) ? s[tid - d] : 0;
        __syncthreads();
        s[tid] += t;
        __syncthreads();
    }
    if (gid < n) off[gid] = s[tid] - v;          // exclusive
    if (tid == SCAN_B - 1) bsum[blockIdx.x] = s[tid];
}

__global__ void k_scan2(int* __restrict__ bsum, int nb) {
    __shared__ int s[128];
    int tid = threadIdx.x;
    int v = (tid < nb) ? bsum[tid] : 0;
    s[tid] = v;
    __syncthreads();
    for (int d = 1; d < 128; d <<= 1) {
        int t = (tid >= d) ? s[tid - d] : 0;
        __syncthreads();
        s[tid] += t;
        __syncthreads();
    }
    if (tid < nb) bsum[tid] = s[tid] - v;        // exclusive, in place
}

__global__ void k_scan3(int* __restrict__ off, const int* __restrict__ bsum,
                        int* __restrict__ pos, int n) {
    int i = blockIdx.x * blockDim.x + threadIdx.x;
    if (i < n) {
        int o = off[i] + bsum[i / SCAN_B];
        off[i] = o;
        pos[i] = o;
    }
}

__global__ void k_scatter(const int* __restrict__ ei, const float* __restrict__ ew,
                          const float* __restrict__ dinv, int* __restrict__ pos,
                          int* __restrict__ ssrc, float* __restrict__ snorm, int E) {
    int e = blockIdx.x * blockDim.x + threadIdx.x;
    if (e >= E) return;
    int s = ei[e];
    int d = ei[E + e];
    int p = atomicAdd(&pos[d], 1);
    ssrc[p] = s;
    snorm[p] = dinv[s] * ew[e] * dinv[d];
}

// h1[n,c] = sum_k x[n,k] * W1[k,c].  32 nodes/block, x tile in LDS, W from L2.
#define G1_MB 32
#define G1_KT 64
__global__ __launch_bounds__(256) void k_gemm1(const float* __restrict__ x,
                                               const float* __restrict__ W,
                                               float* __restrict__ h, int n) {
    __shared__ float xs[G1_MB][G1_KT];
    int t = threadIdx.x;
    int c = t & 63;
    int g = t >> 6;                      // 0..3
    int n0 = blockIdx.x * G1_MB;
    float acc[8];
#pragma unroll
    for (int j = 0; j < 8; ++j) acc[j] = 0.0f;

    int lr = t >> 3;                     // load row 0..31
    int lk = (t & 7) * 8;                // load col start
    for (int k0 = 0; k0 < FIN; k0 += G1_KT) {
        int node = n0 + lr;
        float4 a = make_float4(0, 0, 0, 0), b = make_float4(0, 0, 0, 0);
        if (node < n) {
            const float* src = &x[(size_t)node * FIN + k0 + lk];
            a = *(const float4*)src;
            b = *(const float4*)(src + 4);
        }
        __syncthreads();
        *(float4*)&xs[lr][lk] = a;
        *(float4*)&xs[lr][lk + 4] = b;
        __syncthreads();
#pragma unroll 4
        for (int q = 0; q < G1_KT; q += 4) {
            float w0 = W[(k0 + q + 0) * FHID + c];
            float w1 = W[(k0 + q + 1) * FHID + c];
            float w2 = W[(k0 + q + 2) * FHID + c];
            float w3 = W[(k0 + q + 3) * FHID + c];
#pragma unroll
            for (int j = 0; j < 8; ++j) {
                float4 xv = *(const float4*)&xs[g * 8 + j][q];
                acc[j] += xv.x * w0 + xv.y * w1 + xv.z * w2 + xv.w * w3;
            }
        }
    }
#pragma unroll
    for (int j = 0; j < 8; ++j) {
        int node = n0 + g * 8 + j;
        if (node < n) h[(size_t)node * FHID + c] = acc[j];
    }
}

// z1[d,:] = relu(b1 + sum_{e in CSR(d)} norm_e * h1[src_e,:] + dinv_d^2 * h1[d,:])
__global__ __launch_bounds__(256) void k_agg1(const float* __restrict__ h1,
                                              const int* __restrict__ off,
                                              const int* __restrict__ cnt,
                                              const int* __restrict__ ssrc,
                                              const float* __restrict__ snorm,
                                              const float* __restrict__ dinv,
                                              const float* __restrict__ b1,
                                              float* __restrict__ z1, int n) {
    int wid = (blockIdx.x * blockDim.x + threadIdx.x) >> 6;
    int lane = threadIdx.x & 63;
    if (wid >= n) return;
    int d = wid;
    float di = dinv[d];
    float acc = di * di * h1[(size_t)d * FHID + lane];
    int start = off[d];
    int m = cnt[d];
    for (int i = 0; i < m; ++i) {
        int s = ssrc[start + i];
        float w = snorm[start + i];
        acc += w * h1[(size_t)s * FHID + lane];
    }
    acc += b1[lane];
    z1[(size_t)d * FHID + lane] = fmaxf(acc, 0.0f);
}

// h2[n,c] = sum_k z1[n,k]*W2[k,c]; wave per node, z1 row in regs via shfl.
__global__ __launch_bounds__(256) void k_gemm2(const float* __restrict__ z1,
                                               const float* __restrict__ W2,
                                               float* __restrict__ h2, int n) {
    __shared__ float ws[FHID * FOUT + 64];   // padded: lanes >=40 index past 2560
    for (int i = threadIdx.x; i < FHID * FOUT + 64; i += 256)
        ws[i] = (i < FHID * FOUT) ? W2[i] : 0.0f;
    __syncthreads();
    int wid = (blockIdx.x * blockDim.x + threadIdx.x) >> 6;
    int lane = threadIdx.x & 63;
    if (wid >= n) return;
    float v = z1[(size_t)wid * FHID + lane];
    float acc = 0.0f;
#pragma unroll 8
    for (int k = 0; k < FHID; ++k) {
        float zk = __shfl(v, k, 64);
        acc += zk * ws[k * FOUT + lane];
    }
    if (lane < FOUT) h2[(size_t)wid * FOUT + lane] = acc;
}

// out[d,:] = log_softmax(b2 + agg of h2)
__global__ __launch_bounds__(256) void k_agg2(const float* __restrict__ h2,
                                              const int* __restrict__ off,
                                              const int* __restrict__ cnt,
                                              const int* __restrict__ ssrc,
                                              const float* __restrict__ snorm,
                                              const float* __restrict__ dinv,
                                              const float* __restrict__ b2,
                                              float* __restrict__ out, int n) {
    int wid = (blockIdx.x * blockDim.x + threadIdx.x) >> 6;
    int lane = threadIdx.x & 63;
    if (wid >= n) return;
    int d = wid;
    int cl = (lane < FOUT) ? lane : (FOUT - 1);  // clamp to stay in-bounds
    float di = dinv[d];
    float acc = di * di * h2[(size_t)d * FOUT + cl];
    int start = off[d];
    int m = cnt[d];
    for (int i = 0; i < m; ++i) {
        int s = ssrc[start + i];
        float w = snorm[start + i];
        acc += w * h2[(size_t)s * FOUT + cl];
    }
    acc += b2[cl];
    float mv = (lane < FOUT) ? acc : -INFINITY;
#pragma unroll
    for (int o = 32; o > 0; o >>= 1) mv = fmaxf(mv, __shfl_xor(mv, o, 64));
    float ex = (lane < FOUT) ? expf(acc - mv) : 0.0f;
    float ssum = ex;
#pragma unroll
    for (int o = 32; o > 0; o >>= 1) ssum += __shfl_xor(ssum, o, 64);
    if (lane < FOUT) out[(size_t)d * FOUT + lane] = acc - mv - logf(ssum);
}

extern "C" void kernel_launch(void* const* d_in, const int* in_sizes, int n_in,
                              void* d_out, int out_size, void* d_ws, size_t ws_size,
                              hipStream_t stream) {
    const float* x   = (const float*)d_in[0];
    const int*   ei  = (const int*)d_in[1];     // int64 in ref -> int32 from harness
    const float* ew  = (const float*)d_in[2];
    const float* W1  = (const float*)d_in[3];
    const float* b1  = (const float*)d_in[4];
    const float* W2  = (const float*)d_in[5];
    const float* b2  = (const float*)d_in[6];
    float* out       = (float*)d_out;

    const int N = in_sizes[0] / FIN;      // 100000
    const int E = in_sizes[2];            // 3200000

    char* w = (char*)d_ws;
    auto alloc = [&](size_t bytes) -> char* {
        char* p = w;
        w += (bytes + 255) & ~(size_t)255;
        return p;
    };
    float* deg   = (float*)alloc((size_t)N * 4);            // later holds dinv
    int*   cnt   = (int*)  alloc((size_t)N * 4);
    int*   off   = (int*)  alloc((size_t)N * 4);
    int*   pos   = (int*)  alloc((size_t)N * 4);
    int*   bsum  = (int*)  alloc(((N + SCAN_B - 1) / SCAN_B) * 4);
    int*   ssrc  = (int*)  alloc((size_t)E * 4);
    float* snorm = (float*)alloc((size_t)E * 4);
    float* h1    = (float*)alloc((size_t)N * FHID * 4);     // reused as h2
    float* z1    = (float*)alloc((size_t)N * FHID * 4);
    float* h2    = h1;
    (void)ws_size; (void)n_in; (void)out_size;

    hipMemsetAsync(cnt, 0, (size_t)N * 4, stream);
    k_deg_init<<<(N + 255) / 256, 256, 0, stream>>>(deg, N);
    k_edge_pass1<<<(E + 255) / 256, 256, 0, stream>>>(ei, ew, deg, cnt, E);
    k_dinv<<<(N + 255) / 256, 256, 0, stream>>>(deg, N);
    int nb = (N + SCAN_B - 1) / SCAN_B;
    k_scan1<<<nb, SCAN_B, 0, stream>>>(cnt, off, bsum, N);
    k_scan2<<<1, 128, 0, stream>>>(bsum, nb);
    k_scan3<<<(N + 255) / 256, 256, 0, stream>>>(off, bsum, pos, N);
    k_scatter<<<(E + 255) / 256, 256, 0, stream>>>(ei, ew, deg, pos, ssrc, snorm, E);
    k_gemm1<<<(N + G1_MB - 1) / G1_MB, 256, 0, stream>>>(x, W1, h1, N);
    k_agg1<<<(N + 3) / 4, 256, 0, stream>>>(h1, off, cnt, ssrc, snorm, deg, b1, z1, N);
    k_gemm2<<<(N + 3) / 4, 256, 0, stream>>>(z1, W2, h2, N);
    k_agg2<<<(N + 3) / 4, 256, 0, stream>>>(h2, off, cnt, ssrc, snorm, deg, b2, out, N);
}

// Round 10
// 1176.847 us; speedup vs baseline: 1.3505x; 1.3505x over previous
//
#include <hip/hip_runtime.h>
#include <math.h>

// GCN 2-layer forward, MI355X.
//   init -> edge_pass1 (deg,cnt atomics) -> scan -> scatter (packed 8B recs)
//   -> gemm1 (f32 compute, bf16 out) -> agg1 (bf16 gather, +b1, relu, bf16 out)
//   -> gemm2 (bf16 in, bf16 out) -> agg2 (bf16 gather, +b2, log_softmax, f32 out)
// bf16 intermediates halve gather traffic (agg is L2-miss bound: round-2 profile
// showed FETCH 374MB vs 25.6MB buffer, VALUBusy 16%, HBM 18%).

#define FIN 512
#define FHID 64
#define FOUT 40
#define SCAN_B 1024

typedef unsigned short ushort_t;
typedef unsigned int uint_t;

static __device__ __forceinline__ float bf2f(ushort_t u) {
    return __uint_as_float(((uint_t)u) << 16);
}
// f32 -> bf16 round-to-nearest-even, bit ops (no __hip_bfloat16.data on this ROCm)
static __device__ __forceinline__ ushort_t f2bf(float f) {
    uint_t u = __float_as_uint(f);
    u += 0x7FFFu + ((u >> 16) & 1u);
    return (ushort_t)(u >> 16);
}

__global__ void k_init(float* __restrict__ deg, int* __restrict__ cnt, int n) {
    int i = blockIdx.x * blockDim.x + threadIdx.x;
    if (i < n) { deg[i] = 1.0f; cnt[i] = 0; }   // self-loop weight 1
}

__global__ void k_edge_pass1(const int* __restrict__ ei,
                             const float* __restrict__ ew,
                             float* __restrict__ deg, int* __restrict__ cnt, int E) {
    int e = blockIdx.x * blockDim.x + threadIdx.x;
    if (e >= E) return;
    int d = ei[E + e];
    atomicAdd(&deg[d], ew[e]);
    atomicAdd(&cnt[d], 1);
}

__global__ void k_scan1(const int* __restrict__ cnt, int* __restrict__ off,
                        int* __restrict__ bsum, int n) {
    __shared__ int s[SCAN_B];
    int tid = threadIdx.x;
    int gid = blockIdx.x * SCAN_B + tid;
    int v = (gid < n) ? cnt[gid] : 0;
    s[tid] = v;
    __syncthreads();
    for (int d = 1; d < SCAN_B; d <<= 1) {
        int t = (tid >= d) ? s[tid - d] : 0;
        __syncthreads();
        s[tid] += t;
        __syncthreads();
    }
    if (gid < n) off[gid] = s[tid] - v;          // exclusive
    if (tid == SCAN_B - 1) bsum[blockIdx.x] = s[tid];
}

__global__ void k_scan2(int* __restrict__ bsum, int nb) {
    __shared__ int s[128];
    int tid = threadIdx.x;
    int v = (tid < nb) ? bsum[tid] : 0;
    s[tid] = v;
    __syncthreads();
    for (int d = 1; d < 128; d <<= 1) {
        int t = (tid >= d) ? s[tid - d] : 0;
        __syncthreads();
        s[tid] += t;
        __syncthreads();
    }
    if (tid < nb) bsum[tid] = s[tid] - v;        // exclusive, in place
}

// scan3 + dinv fused (both per-node, dinv only needed after this point)
__global__ void k_scan3(int* __restrict__ off, const int* __restrict__ bsum,
                        int* __restrict__ pos, float* __restrict__ deg, int n) {
    int i = blockIdx.x * blockDim.x + threadIdx.x;
    if (i < n) {
        int o = off[i] + bsum[i / SCAN_B];
        off[i] = o;
        pos[i] = o;
        float v = deg[i];
        deg[i] = (v > 0.0f) ? rsqrtf(v) : 0.0f;  // deg now holds dinv
    }
}

// packed edge record: .x = src, .y = norm (as bits)
__global__ void k_scatter(const int* __restrict__ ei, const float* __restrict__ ew,
                          const float* __restrict__ dinv, int* __restrict__ pos,
                          int2* __restrict__ rec, int E) {
    int e = blockIdx.x * blockDim.x + threadIdx.x;
    if (e >= E) return;
    int s = ei[e];
    int d = ei[E + e];
    int p = atomicAdd(&pos[d], 1);
    int2 r;
    r.x = s;
    r.y = __float_as_int(dinv[s] * ew[e] * dinv[d]);
    rec[p] = r;
}

// h1[n,c] = sum_k x[n,k] * W1[k,c].  32 nodes/block, x tile in LDS, W from L2.
#define G1_MB 32
#define G1_KT 64
__global__ __launch_bounds__(256) void k_gemm1(const float* __restrict__ x,
                                               const float* __restrict__ W,
                                               ushort_t* __restrict__ h, int n) {
    __shared__ float xs[G1_MB][G1_KT];
    int t = threadIdx.x;
    int c = t & 63;
    int g = t >> 6;                      // 0..3
    int n0 = blockIdx.x * G1_MB;
    float acc[8];
#pragma unroll
    for (int j = 0; j < 8; ++j) acc[j] = 0.0f;

    int lr = t >> 3;                     // load row 0..31
    int lk = (t & 7) * 8;                // load col start
    for (int k0 = 0; k0 < FIN; k0 += G1_KT) {
        int node = n0 + lr;
        float4 a = make_float4(0, 0, 0, 0), b = make_float4(0, 0, 0, 0);
        if (node < n) {
            const float* src = &x[(size_t)node * FIN + k0 + lk];
            a = *(const float4*)src;
            b = *(const float4*)(src + 4);
        }
        __syncthreads();
        *(float4*)&xs[lr][lk] = a;
        *(float4*)&xs[lr][lk + 4] = b;
        __syncthreads();
#pragma unroll 4
        for (int q = 0; q < G1_KT; q += 4) {
            float w0 = W[(k0 + q + 0) * FHID + c];
            float w1 = W[(k0 + q + 1) * FHID + c];
            float w2 = W[(k0 + q + 2) * FHID + c];
            float w3 = W[(k0 + q + 3) * FHID + c];
#pragma unroll
            for (int j = 0; j < 8; ++j) {
                float4 xv = *(const float4*)&xs[g * 8 + j][q];
                acc[j] += xv.x * w0 + xv.y * w1 + xv.z * w2 + xv.w * w3;
            }
        }
    }
#pragma unroll
    for (int j = 0; j < 8; ++j) {
        int node = n0 + g * 8 + j;
        if (node < n) h[(size_t)node * FHID + c] = f2bf(acc[j]);
    }
}

// z1[d,:] = relu(b1 + sum_e norm_e * h1[src_e,:] + dinv_d^2 * h1[d,:]); bf16 in/out
__global__ __launch_bounds__(256) void k_agg1(const ushort_t* __restrict__ h1,
                                              const int* __restrict__ off,
                                              const int* __restrict__ cnt,
                                              const int2* __restrict__ rec,
                                              const float* __restrict__ dinv,
                                              const float* __restrict__ b1,
                                              ushort_t* __restrict__ z1, int n) {
    int wid = (blockIdx.x * blockDim.x + threadIdx.x) >> 6;
    int lane = threadIdx.x & 63;
    if (wid >= n) return;
    int d = wid;
    float di = dinv[d];
    float acc = di * di * bf2f(h1[(size_t)d * FHID + lane]);
    int start = off[d];
    int m = cnt[d];
    int i = 0;
    for (; i + 4 <= m; i += 4) {
        int2 r0 = rec[start + i + 0];
        int2 r1 = rec[start + i + 1];
        int2 r2 = rec[start + i + 2];
        int2 r3 = rec[start + i + 3];
        ushort_t u0 = h1[(size_t)r0.x * FHID + lane];
        ushort_t u1 = h1[(size_t)r1.x * FHID + lane];
        ushort_t u2 = h1[(size_t)r2.x * FHID + lane];
        ushort_t u3 = h1[(size_t)r3.x * FHID + lane];
        acc += __int_as_float(r0.y) * bf2f(u0);
        acc += __int_as_float(r1.y) * bf2f(u1);
        acc += __int_as_float(r2.y) * bf2f(u2);
        acc += __int_as_float(r3.y) * bf2f(u3);
    }
    for (; i < m; ++i) {
        int2 r = rec[start + i];
        acc += __int_as_float(r.y) * bf2f(h1[(size_t)r.x * FHID + lane]);
    }
    acc += b1[lane];
    z1[(size_t)d * FHID + lane] = f2bf(fmaxf(acc, 0.0f));
}

// h2[n,c] = sum_k z1[n,k]*W2[k,c]; wave per node, z1 bf16 row via shfl, bf16 out.
__global__ __launch_bounds__(256) void k_gemm2(const ushort_t* __restrict__ z1,
                                               const float* __restrict__ W2,
                                               ushort_t* __restrict__ h2, int n) {
    __shared__ float ws[FHID * FOUT + 64];   // padded: lanes >=40 index past 2560
    for (int i = threadIdx.x; i < FHID * FOUT + 64; i += 256)
        ws[i] = (i < FHID * FOUT) ? W2[i] : 0.0f;
    __syncthreads();
    int wid = (blockIdx.x * blockDim.x + threadIdx.x) >> 6;
    int lane = threadIdx.x & 63;
    if (wid >= n) return;
    float v = bf2f(z1[(size_t)wid * FHID + lane]);
    float acc = 0.0f;
#pragma unroll 8
    for (int k = 0; k < FHID; ++k) {
        float zk = __shfl(v, k, 64);
        acc += zk * ws[k * FOUT + lane];
    }
    if (lane < FOUT) h2[(size_t)wid * FOUT + lane] = f2bf(acc);
}

// out[d,:] = log_softmax(b2 + agg of h2); bf16 gather, f32 out.
__global__ __launch_bounds__(256) void k_agg2(const ushort_t* __restrict__ h2,
                                              const int* __restrict__ off,
                                              const int* __restrict__ cnt,
                                              const int2* __restrict__ rec,
                                              const float* __restrict__ dinv,
                                              const float* __restrict__ b2,
                                              float* __restrict__ out, int n) {
    int wid = (blockIdx.x * blockDim.x + threadIdx.x) >> 6;
    int lane = threadIdx.x & 63;
    if (wid >= n) return;
    int d = wid;
    int cl = (lane < FOUT) ? lane : (FOUT - 1);  // clamp to stay in-bounds
    float di = dinv[d];
    float acc = di * di * bf2f(h2[(size_t)d * FOUT + cl]);
    int start = off[d];
    int m = cnt[d];
    int i = 0;
    for (; i + 4 <= m; i += 4) {
        int2 r0 = rec[start + i + 0];
        int2 r1 = rec[start + i + 1];
        int2 r2 = rec[start + i + 2];
        int2 r3 = rec[start + i + 3];
        ushort_t u0 = h2[(size_t)r0.x * FOUT + cl];
        ushort_t u1 = h2[(size_t)r1.x * FOUT + cl];
        ushort_t u2 = h2[(size_t)r2.x * FOUT + cl];
        ushort_t u3 = h2[(size_t)r3.x * FOUT + cl];
        acc += __int_as_float(r0.y) * bf2f(u0);
        acc += __int_as_float(r1.y) * bf2f(u1);
        acc += __int_as_float(r2.y) * bf2f(u2);
        acc += __int_as_float(r3.y) * bf2f(u3);
    }
    for (; i < m; ++i) {
        int2 r = rec[start + i];
        acc += __int_as_float(r.y) * bf2f(h2[(size_t)r.x * FOUT + cl]);
    }
    acc += b2[cl];
    float mv = (lane < FOUT) ? acc : -INFINITY;
#pragma unroll
    for (int o = 32; o > 0; o >>= 1) mv = fmaxf(mv, __shfl_xor(mv, o, 64));
    float ex = (lane < FOUT) ? expf(acc - mv) : 0.0f;
    float ssum = ex;
#pragma unroll
    for (int o = 32; o > 0; o >>= 1) ssum += __shfl_xor(ssum, o, 64);
    if (lane < FOUT) out[(size_t)d * FOUT + lane] = acc - mv - logf(ssum);
}

extern "C" void kernel_launch(void* const* d_in, const int* in_sizes, int n_in,
                              void* d_out, int out_size, void* d_ws, size_t ws_size,
                              hipStream_t stream) {
    const float* x   = (const float*)d_in[0];
    const int*   ei  = (const int*)d_in[1];     // int64 in ref -> int32 from harness
    const float* ew  = (const float*)d_in[2];
    const float* W1  = (const float*)d_in[3];
    const float* b1  = (const float*)d_in[4];
    const float* W2  = (const float*)d_in[5];
    const float* b2  = (const float*)d_in[6];
    float* out       = (float*)d_out;

    const int N = in_sizes[0] / FIN;      // 100000
    const int E = in_sizes[2];            // 3200000

    char* w = (char*)d_ws;
    auto alloc = [&](size_t bytes) -> char* {
        char* p = w;
        w += (bytes + 255) & ~(size_t)255;
        return p;
    };
    float*    deg   = (float*)alloc((size_t)N * 4);          // later holds dinv
    int*      cnt   = (int*)  alloc((size_t)N * 4);
    int*      off   = (int*)  alloc((size_t)N * 4);
    int*      pos   = (int*)  alloc((size_t)N * 4);
    int*      bsum  = (int*)  alloc(((N + SCAN_B - 1) / SCAN_B) * 4);
    int2*     rec   = (int2*) alloc((size_t)E * 8);
    ushort_t* h1    = (ushort_t*)alloc((size_t)N * FHID * 2);
    ushort_t* z1    = (ushort_t*)alloc((size_t)N * FHID * 2);
    ushort_t* h2    = (ushort_t*)alloc((size_t)N * FOUT * 2);
    (void)ws_size; (void)n_in; (void)out_size;

    k_init<<<(N + 255) / 256, 256, 0, stream>>>(deg, cnt, N);
    k_edge_pass1<<<(E + 255) / 256, 256, 0, stream>>>(ei, ew, deg, cnt, E);
    int nb = (N + SCAN_B - 1) / SCAN_B;
    k_scan1<<<nb, SCAN_B, 0, stream>>>(cnt, off, bsum, N);
    k_scan2<<<1, 128, 0, stream>>>(bsum, nb);
    k_scan3<<<(N + 255) / 256, 256, 0, stream>>>(off, bsum, pos, deg, N);
    k_scatter<<<(E + 255) / 256, 256, 0, stream>>>(ei, ew, deg, pos, rec, E);
    k_gemm1<<<(N + G1_MB - 1) / G1_MB, 256, 0, stream>>>(x, W1, h1, N);
    k_agg1<<<(N + 3) / 4, 256, 0, stream>>>(h1, off, cnt, rec, deg, b1, z1, N);
    k_gemm2<<<(N + 3) / 4, 256, 0, stream>>>(z1, W2, h2, N);
    k_agg2<<<(N + 3) / 4, 256, 0, stream>>>(h2, off, cnt, rec, deg, b2, out, N);
}

// Round 12
// 1045.602 us; speedup vs baseline: 1.5200x; 1.1255x over previous
//
#include <hip/hip_runtime.h>
#include <math.h>

// GCN 2-layer forward, MI355X.
// Round-11 change: edge_pass1's two atomics (float deg + int cnt) fused into ONE
// u64 atomic per edge: [count:16 | weight-sum fixed-point 2^-30 : 48].
// Rationale: round-10 profile shows edge_pass1 = 278us, VALUBusy 0.3%,
// WRITE_SIZE 199.6MB = 6.4M atomics x 32B memory-side RMW -> transaction-bound.

#define FIN 512
#define FHID 64
#define FOUT 40
#define SCAN_B 1024
#define FIX_SCALE 1073741824.0f   // 2^30
#define FIX_MASK  0xFFFFFFFFFFFFull

typedef unsigned short ushort_t;
typedef unsigned int uint_t;
typedef unsigned long long u64_t;

static __device__ __forceinline__ float bf2f(ushort_t u) {
    return __uint_as_float(((uint_t)u) << 16);
}
// f32 -> bf16 round-to-nearest-even, bit ops (no __hip_bfloat16.data on this ROCm)
static __device__ __forceinline__ ushort_t f2bf(float f) {
    uint_t u = __float_as_uint(f);
    u += 0x7FFFu + ((u >> 16) & 1u);
    return (ushort_t)(u >> 16);
}

// packed[i] = [cnt:16 | sum(ew)+1.0 in 2^-30 fixed point : 48]; init sum=1.0 (self-loop)
__global__ void k_init(u64_t* __restrict__ packed, int n) {
    int i = blockIdx.x * blockDim.x + threadIdx.x;
    if (i < n) packed[i] = (u64_t)1 << 30;
}

__global__ void k_edge_pass1(const int* __restrict__ ei,
                             const float* __restrict__ ew,
                             u64_t* __restrict__ packed, int E) {
    int e = blockIdx.x * blockDim.x + threadIdx.x;
    if (e >= E) return;
    int d = ei[E + e];
    u64_t v = ((u64_t)1 << 48) | (u64_t)(ew[e] * FIX_SCALE + 0.5f);
    atomicAdd(&packed[d], v);
}

__global__ void k_scan1(const u64_t* __restrict__ packed, int* __restrict__ off,
                        int* __restrict__ bsum, int n) {
    __shared__ int s[SCAN_B];
    int tid = threadIdx.x;
    int gid = blockIdx.x * SCAN_B + tid;
    int v = (gid < n) ? (int)(packed[gid] >> 48) : 0;
    s[tid] = v;
    __syncthreads();
    for (int d = 1; d < SCAN_B; d <<= 1) {
        int t = (tid >= d) ? s[tid - d] : 0;
        __syncthreads();
        s[tid] += t;
        __syncthreads();
    }
    if (gid < n) off[gid] = s[tid] - v;          // exclusive
    if (tid == SCAN_B - 1) bsum[blockIdx.x] = s[tid];
}

__global__ void k_scan2(int* __restrict__ bsum, int nb) {
    __shared__ int s[128];
    int tid = threadIdx.x;
    int v = (tid < nb) ? bsum[tid] : 0;
    s[tid] = v;
    __syncthreads();
    for (int d = 1; d < 128; d <<= 1) {
        int t = (tid >= d) ? s[tid - d] : 0;
        __syncthreads();
        s[tid] += t;
        __syncthreads();
    }
    if (tid < nb) bsum[tid] = s[tid] - v;        // exclusive, in place
}

// scan3: finalize offsets, duplicate into pos, compute dinv from packed sum
__global__ void k_scan3(int* __restrict__ off, const int* __restrict__ bsum,
                        int* __restrict__ pos, const u64_t* __restrict__ packed,
                        float* __restrict__ dinv, int n) {
    int i = blockIdx.x * blockDim.x + threadIdx.x;
    if (i < n) {
        int o = off[i] + bsum[i / SCAN_B];
        off[i] = o;
        pos[i] = o;
        float deg = (float)(packed[i] & FIX_MASK) * (1.0f / FIX_SCALE);
        dinv[i] = rsqrtf(deg);   // deg >= 1.0 always (self-loop)
    }
}

// packed edge record: .x = src, .y = norm (as bits)
__global__ void k_scatter(const int* __restrict__ ei, const float* __restrict__ ew,
                          const float* __restrict__ dinv, int* __restrict__ pos,
                          int2* __restrict__ rec, int E) {
    int e = blockIdx.x * blockDim.x + threadIdx.x;
    if (e >= E) return;
    int s = ei[e];
    int d = ei[E + e];
    int p = atomicAdd(&pos[d], 1);
    int2 r;
    r.x = s;
    r.y = __float_as_int(dinv[s] * ew[e] * dinv[d]);
    rec[p] = r;
}

// h1[n,c] = sum_k x[n,k] * W1[k,c].  32 nodes/block, x tile in LDS, W from L2.
#define G1_MB 32
#define G1_KT 64
__global__ __launch_bounds__(256) void k_gemm1(const float* __restrict__ x,
                                               const float* __restrict__ W,
                                               ushort_t* __restrict__ h, int n) {
    __shared__ float xs[G1_MB][G1_KT];
    int t = threadIdx.x;
    int c = t & 63;
    int g = t >> 6;                      // 0..3
    int n0 = blockIdx.x * G1_MB;
    float acc[8];
#pragma unroll
    for (int j = 0; j < 8; ++j) acc[j] = 0.0f;

    int lr = t >> 3;                     // load row 0..31
    int lk = (t & 7) * 8;                // load col start
    for (int k0 = 0; k0 < FIN; k0 += G1_KT) {
        int node = n0 + lr;
        float4 a = make_float4(0, 0, 0, 0), b = make_float4(0, 0, 0, 0);
        if (node < n) {
            const float* src = &x[(size_t)node * FIN + k0 + lk];
            a = *(const float4*)src;
            b = *(const float4*)(src + 4);
        }
        __syncthreads();
        *(float4*)&xs[lr][lk] = a;
        *(float4*)&xs[lr][lk + 4] = b;
        __syncthreads();
#pragma unroll 4
        for (int q = 0; q < G1_KT; q += 4) {
            float w0 = W[(k0 + q + 0) * FHID + c];
            float w1 = W[(k0 + q + 1) * FHID + c];
            float w2 = W[(k0 + q + 2) * FHID + c];
            float w3 = W[(k0 + q + 3) * FHID + c];
#pragma unroll
            for (int j = 0; j < 8; ++j) {
                float4 xv = *(const float4*)&xs[g * 8 + j][q];
                acc[j] += xv.x * w0 + xv.y * w1 + xv.z * w2 + xv.w * w3;
            }
        }
    }
#pragma unroll
    for (int j = 0; j < 8; ++j) {
        int node = n0 + g * 8 + j;
        if (node < n) h[(size_t)node * FHID + c] = f2bf(acc[j]);
    }
}

// z1[d,:] = relu(b1 + sum_e norm_e * h1[src_e,:] + dinv_d^2 * h1[d,:]); bf16 in/out
__global__ __launch_bounds__(256) void k_agg1(const ushort_t* __restrict__ h1,
                                              const int* __restrict__ off,
                                              const u64_t* __restrict__ packed,
                                              const int2* __restrict__ rec,
                                              const float* __restrict__ dinv,
                                              const float* __restrict__ b1,
                                              ushort_t* __restrict__ z1, int n) {
    int wid = (blockIdx.x * blockDim.x + threadIdx.x) >> 6;
    int lane = threadIdx.x & 63;
    if (wid >= n) return;
    int d = wid;
    float di = dinv[d];
    float acc = di * di * bf2f(h1[(size_t)d * FHID + lane]);
    int start = off[d];
    int m = (int)(packed[d] >> 48);
    int i = 0;
    for (; i + 4 <= m; i += 4) {
        int2 r0 = rec[start + i + 0];
        int2 r1 = rec[start + i + 1];
        int2 r2 = rec[start + i + 2];
        int2 r3 = rec[start + i + 3];
        ushort_t u0 = h1[(size_t)r0.x * FHID + lane];
        ushort_t u1 = h1[(size_t)r1.x * FHID + lane];
        ushort_t u2 = h1[(size_t)r2.x * FHID + lane];
        ushort_t u3 = h1[(size_t)r3.x * FHID + lane];
        acc += __int_as_float(r0.y) * bf2f(u0);
        acc += __int_as_float(r1.y) * bf2f(u1);
        acc += __int_as_float(r2.y) * bf2f(u2);
        acc += __int_as_float(r3.y) * bf2f(u3);
    }
    for (; i < m; ++i) {
        int2 r = rec[start + i];
        acc += __int_as_float(r.y) * bf2f(h1[(size_t)r.x * FHID + lane]);
    }
    acc += b1[lane];
    z1[(size_t)d * FHID + lane] = f2bf(fmaxf(acc, 0.0f));
}

// h2[n,c] = sum_k z1[n,k]*W2[k,c]; wave per node, z1 bf16 row via shfl, bf16 out.
__global__ __launch_bounds__(256) void k_gemm2(const ushort_t* __restrict__ z1,
                                               const float* __restrict__ W2,
                                               ushort_t* __restrict__ h2, int n) {
    __shared__ float ws[FHID * FOUT + 64];   // padded: lanes >=40 index past 2560
    for (int i = threadIdx.x; i < FHID * FOUT + 64; i += 256)
        ws[i] = (i < FHID * FOUT) ? W2[i] : 0.0f;
    __syncthreads();
    int wid = (blockIdx.x * blockDim.x + threadIdx.x) >> 6;
    int lane = threadIdx.x & 63;
    if (wid >= n) return;
    float v = bf2f(z1[(size_t)wid * FHID + lane]);
    float acc = 0.0f;
#pragma unroll 8
    for (int k = 0; k < FHID; ++k) {
        float zk = __shfl(v, k, 64);
        acc += zk * ws[k * FOUT + lane];
    }
    if (lane < FOUT) h2[(size_t)wid * FOUT + lane] = f2bf(acc);
}

// out[d,:] = log_softmax(b2 + agg of h2); bf16 gather, f32 out.
__global__ __launch_bounds__(256) void k_agg2(const ushort_t* __restrict__ h2,
                                              const int* __restrict__ off,
                                              const u64_t* __restrict__ packed,
                                              const int2* __restrict__ rec,
                                              const float* __restrict__ dinv,
                                              const float* __restrict__ b2,
                                              float* __restrict__ out, int n) {
    int wid = (blockIdx.x * blockDim.x + threadIdx.x) >> 6;
    int lane = threadIdx.x & 63;
    if (wid >= n) return;
    int d = wid;
    int cl = (lane < FOUT) ? lane : (FOUT - 1);  // clamp to stay in-bounds
    float di = dinv[d];
    float acc = di * di * bf2f(h2[(size_t)d * FOUT + cl]);
    int start = off[d];
    int m = (int)(packed[d] >> 48);
    int i = 0;
    for (; i + 4 <= m; i += 4) {
        int2 r0 = rec[start + i + 0];
        int2 r1 = rec[start + i + 1];
        int2 r2 = rec[start + i + 2];
        int2 r3 = rec[start + i + 3];
        ushort_t u0 = h2[(size_t)r0.x * FOUT + cl];
        ushort_t u1 = h2[(size_t)r1.x * FOUT + cl];
        ushort_t u2 = h2[(size_t)r2.x * FOUT + cl];
        ushort_t u3 = h2[(size_t)r3.x * FOUT + cl];
        acc += __int_as_float(r0.y) * bf2f(u0);
        acc += __int_as_float(r1.y) * bf2f(u1);
        acc += __int_as_float(r2.y) * bf2f(u2);
        acc += __int_as_float(r3.y) * bf2f(u3);
    }
    for (; i < m; ++i) {
        int2 r = rec[start + i];
        acc += __int_as_float(r.y) * bf2f(h2[(size_t)r.x * FOUT + cl]);
    }
    acc += b2[cl];
    float mv = (lane < FOUT) ? acc : -INFINITY;
#pragma unroll
    for (int o = 32; o > 0; o >>= 1) mv = fmaxf(mv, __shfl_xor(mv, o, 64));
    float ex = (lane < FOUT) ? expf(acc - mv) : 0.0f;
    float ssum = ex;
#pragma unroll
    for (int o = 32; o > 0; o >>= 1) ssum += __shfl_xor(ssum, o, 64);
    if (lane < FOUT) out[(size_t)d * FOUT + lane] = acc - mv - logf(ssum);
}

extern "C" void kernel_launch(void* const* d_in, const int* in_sizes, int n_in,
                              void* d_out, int out_size, void* d_ws, size_t ws_size,
                              hipStream_t stream) {
    const float* x   = (const float*)d_in[0];
    const int*   ei  = (const int*)d_in[1];     // int64 in ref -> int32 from harness
    const float* ew  = (const float*)d_in[2];
    const float* W1  = (const float*)d_in[3];
    const float* b1  = (const float*)d_in[4];
    const float* W2  = (const float*)d_in[5];
    const float* b2  = (const float*)d_in[6];
    float* out       = (float*)d_out;

    const int N = in_sizes[0] / FIN;      // 100000
    const int E = in_sizes[2];            // 3200000

    char* w = (char*)d_ws;
    auto alloc = [&](size_t bytes) -> char* {
        char* p = w;
        w += (bytes + 255) & ~(size_t)255;
        return p;
    };
    u64_t*    packed = (u64_t*)alloc((size_t)N * 8);   // [cnt:16|fixsum:48]
    float*    dinv   = (float*)alloc((size_t)N * 4);
    int*      off    = (int*)  alloc((size_t)N * 4);
    int*      pos    = (int*)  alloc((size_t)N * 4);
    int*      bsum   = (int*)  alloc(((N + SCAN_B - 1) / SCAN_B) * 4);
    int2*     rec    = (int2*) alloc((size_t)E * 8);
    ushort_t* h1     = (ushort_t*)alloc((size_t)N * FHID * 2);
    ushort_t* z1     = (ushort_t*)alloc((size_t)N * FHID * 2);
    ushort_t* h2     = (ushort_t*)alloc((size_t)N * FOUT * 2);
    (void)ws_size; (void)n_in; (void)out_size;

    k_init<<<(N + 255) / 256, 256, 0, stream>>>(packed, N);
    k_edge_pass1<<<(E + 255) / 256, 256, 0, stream>>>(ei, ew, packed, E);
    int nb = (N + SCAN_B - 1) / SCAN_B;
    k_scan1<<<nb, SCAN_B, 0, stream>>>(packed, off, bsum, N);
    k_scan2<<<1, 128, 0, stream>>>(bsum, nb);
    k_scan3<<<(N + 255) / 256, 256, 0, stream>>>(off, bsum, pos, packed, dinv, N);
    k_scatter<<<(E + 255) / 256, 256, 0, stream>>>(ei, ew, dinv, pos, rec, E);
    k_gemm1<<<(N + G1_MB - 1) / G1_MB, 256, 0, stream>>>(x, W1, h1, N);
    k_agg1<<<(N + 3) / 4, 256, 0, stream>>>(h1, off, packed, rec, dinv, b1, z1, N);
    k_gemm2<<<(N + 3) / 4, 256, 0, stream>>>(z1, W2, h2, N);
    k_agg2<<<(N + 3) / 4, 256, 0, stream>>>(h2, off, packed, rec, dinv, b2, out, N);
}

// Round 15
// 936.610 us; speedup vs baseline: 1.6969x; 1.1164x over previous
//
#include <hip/hip_runtime.h>
#include <math.h>

// GCN 2-layer forward, MI355X.
// Round-13 change: gemm1 f32-VALU -> bf16 MFMA (16x16x32), W1 pre-converted to
// transposed bf16 Wt[64][512] (L2-resident). Round-12 profile: gemm1 223us,
// VALUBusy 65%, MfmaUtil 0 -> f32 vector ceiling; MFMA floor is the 205MB x read.

#define FIN 512
#define FHID 64
#define FOUT 40
#define SCAN_B 1024
#define FIX_SCALE 1073741824.0f   // 2^30
#define FIX_MASK  0xFFFFFFFFFFFFull

typedef unsigned short ushort_t;
typedef unsigned int uint_t;
typedef unsigned long long u64_t;
typedef __attribute__((ext_vector_type(8))) short bf16x8;
typedef __attribute__((ext_vector_type(4))) float f32x4;

static __device__ __forceinline__ float bf2f(ushort_t u) {
    return __uint_as_float(((uint_t)u) << 16);
}
// f32 -> bf16 round-to-nearest-even, bit ops
static __device__ __forceinline__ ushort_t f2bf(float f) {
    uint_t u = __float_as_uint(f);
    u += 0x7FFFu + ((u >> 16) & 1u);
    return (ushort_t)(u >> 16);
}

// packed[i] = [cnt:16 | sum(ew)+1.0 in 2^-30 fixed point : 48]; init sum=1.0 (self-loop)
__global__ void k_init(u64_t* __restrict__ packed, int n) {
    int i = blockIdx.x * blockDim.x + threadIdx.x;
    if (i < n) packed[i] = (u64_t)1 << 30;
}

__global__ void k_edge_pass1(const int* __restrict__ ei,
                             const float* __restrict__ ew,
                             u64_t* __restrict__ packed, int E) {
    int e = blockIdx.x * blockDim.x + threadIdx.x;
    if (e >= E) return;
    int d = ei[E + e];
    u64_t v = ((u64_t)1 << 48) | (u64_t)(ew[e] * FIX_SCALE + 0.5f);
    atomicAdd(&packed[d], v);
}

__global__ void k_scan1(const u64_t* __restrict__ packed, int* __restrict__ off,
                        int* __restrict__ bsum, int n) {
    __shared__ int s[SCAN_B];
    int tid = threadIdx.x;
    int gid = blockIdx.x * SCAN_B + tid;
    int v = (gid < n) ? (int)(packed[gid] >> 48) : 0;
    s[tid] = v;
    __syncthreads();
    for (int d = 1; d < SCAN_B; d <<= 1) {
        int t = (tid >= d) ? s[tid - d] : 0;
        __syncthreads();
        s[tid] += t;
        __syncthreads();
    }
    if (gid < n) off[gid] = s[tid] - v;          // exclusive
    if (tid == SCAN_B - 1) bsum[blockIdx.x] = s[tid];
}

__global__ void k_scan2(int* __restrict__ bsum, int nb) {
    __shared__ int s[128];
    int tid = threadIdx.x;
    int v = (tid < nb) ? bsum[tid] : 0;
    s[tid] = v;
    __syncthreads();
    for (int d = 1; d < 128; d <<= 1) {
        int t = (tid >= d) ? s[tid - d] : 0;
        __syncthreads();
        s[tid] += t;
        __syncthreads();
    }
    if (tid < nb) bsum[tid] = s[tid] - v;        // exclusive, in place
}

// scan3: finalize offsets, duplicate into pos, compute dinv from packed sum
__global__ void k_scan3(int* __restrict__ off, const int* __restrict__ bsum,
                        int* __restrict__ pos, const u64_t* __restrict__ packed,
                        float* __restrict__ dinv, int n) {
    int i = blockIdx.x * blockDim.x + threadIdx.x;
    if (i < n) {
        int o = off[i] + bsum[i / SCAN_B];
        off[i] = o;
        pos[i] = o;
        float deg = (float)(packed[i] & FIX_MASK) * (1.0f / FIX_SCALE);
        dinv[i] = rsqrtf(deg);   // deg >= 1.0 always (self-loop)
    }
}

// packed edge record: .x = src, .y = norm (as bits)
__global__ void k_scatter(const int* __restrict__ ei, const float* __restrict__ ew,
                          const float* __restrict__ dinv, int* __restrict__ pos,
                          int2* __restrict__ rec, int E) {
    int e = blockIdx.x * blockDim.x + threadIdx.x;
    if (e >= E) return;
    int s = ei[e];
    int d = ei[E + e];
    int p = atomicAdd(&pos[d], 1);
    int2 r;
    r.x = s;
    r.y = __float_as_int(dinv[s] * ew[e] * dinv[d]);
    rec[p] = r;
}

// Wt[c][k] = bf16(W1[k][c]); 64x512, 64KB, L2-resident for gemm1.
__global__ void k_convW1(const float* __restrict__ W, ushort_t* __restrict__ Wt) {
    int idx = blockIdx.x * blockDim.x + threadIdx.x;   // 0..32767
    int c = idx >> 9;
    int k = idx & 511;
    Wt[idx] = f2bf(W[k * FHID + c]);
}

// h1 = x @ W1 via bf16 MFMA. Wave = 16 rows x 64 cols (4 16x16 C-tiles).
// A-frag: lane l -> row l&15, k-chunk (l>>4)*8 (f32 loads, cvt to bf16).
// B-frag: lane l -> col l&15 of tile, k-chunk (l>>4)*8 (16B load from Wt).
// C/D: col = lane&15, row = (lane>>4)*4 + j  [m89-verified mapping].
__global__ __launch_bounds__(256) void k_gemm1(const float* __restrict__ x,
                                               const ushort_t* __restrict__ Wt,
                                               ushort_t* __restrict__ h, int n) {
    int t = threadIdx.x;
    int lane = t & 63;
    int wv = t >> 6;
    int row0 = blockIdx.x * 64 + wv * 16;
    if (row0 >= n) return;                    // n % 16 == 0: full tiles only
    int r = lane & 15;
    int kg = lane >> 4;                       // 0..3
    int koff = kg * 8;
    const float* xrow = x + (size_t)(row0 + r) * FIN;
    const ushort_t* wbase = Wt + (size_t)r * FIN + koff;   // col = tile*16 + r
    f32x4 acc0 = {0,0,0,0}, acc1 = {0,0,0,0}, acc2 = {0,0,0,0}, acc3 = {0,0,0,0};
    for (int k0 = 0; k0 < FIN; k0 += 32) {
        float4 a0 = *(const float4*)(xrow + k0 + koff);
        float4 a1 = *(const float4*)(xrow + k0 + koff + 4);
        bf16x8 af;
        af[0] = (short)f2bf(a0.x); af[1] = (short)f2bf(a0.y);
        af[2] = (short)f2bf(a0.z); af[3] = (short)f2bf(a0.w);
        af[4] = (short)f2bf(a1.x); af[5] = (short)f2bf(a1.y);
        af[6] = (short)f2bf(a1.z); af[7] = (short)f2bf(a1.w);
        bf16x8 b0 = *(const bf16x8*)(wbase + k0);
        bf16x8 b1 = *(const bf16x8*)(wbase + k0 + 16 * FIN);
        bf16x8 b2 = *(const bf16x8*)(wbase + k0 + 32 * FIN);
        bf16x8 b3 = *(const bf16x8*)(wbase + k0 + 48 * FIN);
        acc0 = __builtin_amdgcn_mfma_f32_16x16x32_bf16(af, b0, acc0, 0, 0, 0);
        acc1 = __builtin_amdgcn_mfma_f32_16x16x32_bf16(af, b1, acc1, 0, 0, 0);
        acc2 = __builtin_amdgcn_mfma_f32_16x16x32_bf16(af, b2, acc2, 0, 0, 0);
        acc3 = __builtin_amdgcn_mfma_f32_16x16x32_bf16(af, b3, acc3, 0, 0, 0);
    }
    ushort_t* hb = h + (size_t)(row0 + kg * 4) * FHID + r;
#pragma unroll
    for (int j = 0; j < 4; ++j) {
        hb[(size_t)j * FHID +  0] = f2bf(acc0[j]);
        hb[(size_t)j * FHID + 16] = f2bf(acc1[j]);
        hb[(size_t)j * FHID + 32] = f2bf(acc2[j]);
        hb[(size_t)j * FHID + 48] = f2bf(acc3[j]);
    }
}

// z1[d,:] = relu(b1 + sum_e norm_e * h1[src_e,:] + dinv_d^2 * h1[d,:]); bf16 in/out
__global__ __launch_bounds__(256) void k_agg1(const ushort_t* __restrict__ h1,
                                              const int* __restrict__ off,
                                              const u64_t* __restrict__ packed,
                                              const int2* __restrict__ rec,
                                              const float* __restrict__ dinv,
                                              const float* __restrict__ b1,
                                              ushort_t* __restrict__ z1, int n) {
    int wid = (blockIdx.x * blockDim.x + threadIdx.x) >> 6;
    int lane = threadIdx.x & 63;
    if (wid >= n) return;
    int d = wid;
    float di = dinv[d];
    float acc = di * di * bf2f(h1[(size_t)d * FHID + lane]);
    int start = off[d];
    int m = (int)(packed[d] >> 48);
    int i = 0;
    for (; i + 4 <= m; i += 4) {
        int2 r0 = rec[start + i + 0];
        int2 r1 = rec[start + i + 1];
        int2 r2 = rec[start + i + 2];
        int2 r3 = rec[start + i + 3];
        ushort_t u0 = h1[(size_t)r0.x * FHID + lane];
        ushort_t u1 = h1[(size_t)r1.x * FHID + lane];
        ushort_t u2 = h1[(size_t)r2.x * FHID + lane];
        ushort_t u3 = h1[(size_t)r3.x * FHID + lane];
        acc += __int_as_float(r0.y) * bf2f(u0);
        acc += __int_as_float(r1.y) * bf2f(u1);
        acc += __int_as_float(r2.y) * bf2f(u2);
        acc += __int_as_float(r3.y) * bf2f(u3);
    }
    for (; i < m; ++i) {
        int2 r = rec[start + i];
        acc += __int_as_float(r.y) * bf2f(h1[(size_t)r.x * FHID + lane]);
    }
    acc += b1[lane];
    z1[(size_t)d * FHID + lane] = f2bf(fmaxf(acc, 0.0f));
}

// h2[n,c] = sum_k z1[n,k]*W2[k,c]; wave per node, z1 bf16 row via shfl, bf16 out.
__global__ __launch_bounds__(256) void k_gemm2(const ushort_t* __restrict__ z1,
                                               const float* __restrict__ W2,
                                               ushort_t* __restrict__ h2, int n) {
    __shared__ float ws[FHID * FOUT + 64];   // padded: lanes >=40 index past 2560
    for (int i = threadIdx.x; i < FHID * FOUT + 64; i += 256)
        ws[i] = (i < FHID * FOUT) ? W2[i] : 0.0f;
    __syncthreads();
    int wid = (blockIdx.x * blockDim.x + threadIdx.x) >> 6;
    int lane = threadIdx.x & 63;
    if (wid >= n) return;
    float v = bf2f(z1[(size_t)wid * FHID + lane]);
    float acc = 0.0f;
#pragma unroll 8
    for (int k = 0; k < FHID; ++k) {
        float zk = __shfl(v, k, 64);
        acc += zk * ws[k * FOUT + lane];
    }
    if (lane < FOUT) h2[(size_t)wid * FOUT + lane] = f2bf(acc);
}

// out[d,:] = log_softmax(b2 + agg of h2); bf16 gather, f32 out.
__global__ __launch_bounds__(256) void k_agg2(const ushort_t* __restrict__ h2,
                                              const int* __restrict__ off,
                                              const u64_t* __restrict__ packed,
                                              const int2* __restrict__ rec,
                                              const float* __restrict__ dinv,
                                              const float* __restrict__ b2,
                                              float* __restrict__ out, int n) {
    int wid = (blockIdx.x * blockDim.x + threadIdx.x) >> 6;
    int lane = threadIdx.x & 63;
    if (wid >= n) return;
    int d = wid;
    int cl = (lane < FOUT) ? lane : (FOUT - 1);  // clamp to stay in-bounds
    float di = dinv[d];
    float acc = di * di * bf2f(h2[(size_t)d * FOUT + cl]);
    int start = off[d];
    int m = (int)(packed[d] >> 48);
    int i = 0;
    for (; i + 4 <= m; i += 4) {
        int2 r0 = rec[start + i + 0];
        int2 r1 = rec[start + i + 1];
        int2 r2 = rec[start + i + 2];
        int2 r3 = rec[start + i + 3];
        ushort_t u0 = h2[(size_t)r0.x * FOUT + cl];
        ushort_t u1 = h2[(size_t)r1.x * FOUT + cl];
        ushort_t u2 = h2[(size_t)r2.x * FOUT + cl];
        ushort_t u3 = h2[(size_t)r3.x * FOUT + cl];
        acc += __int_as_float(r0.y) * bf2f(u0);
        acc += __int_as_float(r1.y) * bf2f(u1);
        acc += __int_as_float(r2.y) * bf2f(u2);
        acc += __int_as_float(r3.y) * bf2f(u3);
    }
    for (; i < m; ++i) {
        int2 r = rec[start + i];
        acc += __int_as_float(r.y) * bf2f(h2[(size_t)r.x * FOUT + cl]);
    }
    acc += b2[cl];
    float mv = (lane < FOUT) ? acc : -INFINITY;
#pragma unroll
    for (int o = 32; o > 0; o >>= 1) mv = fmaxf(mv, __shfl_xor(mv, o, 64));
    float ex = (lane < FOUT) ? expf(acc - mv) : 0.0f;
    float ssum = ex;
#pragma unroll
    for (int o = 32; o > 0; o >>= 1) ssum += __shfl_xor(ssum, o, 64);
    if (lane < FOUT) out[(size_t)d * FOUT + lane] = acc - mv - logf(ssum);
}

extern "C" void kernel_launch(void* const* d_in, const int* in_sizes, int n_in,
                              void* d_out, int out_size, void* d_ws, size_t ws_size,
                              hipStream_t stream) {
    const float* x   = (const float*)d_in[0];
    const int*   ei  = (const int*)d_in[1];     // int64 in ref -> int32 from harness
    const float* ew  = (const float*)d_in[2];
    const float* W1  = (const float*)d_in[3];
    const float* b1  = (const float*)d_in[4];
    const float* W2  = (const float*)d_in[5];
    const float* b2  = (const float*)d_in[6];
    float* out       = (float*)d_out;

    const int N = in_sizes[0] / FIN;      // 100000
    const int E = in_sizes[2];            // 3200000

    char* w = (char*)d_ws;
    auto alloc = [&](size_t bytes) -> char* {
        char* p = w;
        w += (bytes + 255) & ~(size_t)255;
        return p;
    };
    u64_t*    packed = (u64_t*)alloc((size_t)N * 8);   // [cnt:16|fixsum:48]
    float*    dinv   = (float*)alloc((size_t)N * 4);
    int*      off    = (int*)  alloc((size_t)N * 4);
    int*      pos    = (int*)  alloc((size_t)N * 4);
    int*      bsum   = (int*)  alloc(((N + SCAN_B - 1) / SCAN_B) * 4);
    int2*     rec    = (int2*) alloc((size_t)E * 8);
    ushort_t* Wt     = (ushort_t*)alloc((size_t)FHID * FIN * 2);  // bf16 W1^T
    ushort_t* h1     = (ushort_t*)alloc((size_t)N * FHID * 2);
    ushort_t* z1     = (ushort_t*)alloc((size_t)N * FHID * 2);
    ushort_t* h2     = (ushort_t*)alloc((size_t)N * FOUT * 2);
    (void)ws_size; (void)n_in; (void)out_size;

    k_init<<<(N + 255) / 256, 256, 0, stream>>>(packed, N);
    k_edge_pass1<<<(E + 255) / 256, 256, 0, stream>>>(ei, ew, packed, E);
    int nb = (N + SCAN_B - 1) / SCAN_B;
    k_scan1<<<nb, SCAN_B, 0, stream>>>(packed, off, bsum, N);
    k_scan2<<<1, 128, 0, stream>>>(bsum, nb);
    k_scan3<<<(N + 255) / 256, 256, 0, stream>>>(off, bsum, pos, packed, dinv, N);
    k_scatter<<<(E + 255) / 256, 256, 0, stream>>>(ei, ew, dinv, pos, rec, E);
    k_convW1<<<(FHID * FIN) / 256, 256, 0, stream>>>(W1, Wt);
    k_gemm1<<<(N + 63) / 64, 256, 0, stream>>>(x, Wt, h1, N);
    k_agg1<<<(N + 3) / 4, 256, 0, stream>>>(h1, off, packed, rec, dinv, b1, z1, N);
    k_gemm2<<<(N + 3) / 4, 256, 0, stream>>>(z1, W2, h2, N);
    k_agg2<<<(N + 3) / 4, 256, 0, stream>>>(h2, off, packed, rec, dinv, b2, out, N);
}